// Round 5
// baseline (2951.389 us; speedup 1.0000x reference)
//
#include <hip/hip_runtime.h>

typedef __attribute__((ext_vector_type(8))) short short8;
typedef __attribute__((ext_vector_type(4))) float f32x4;
typedef unsigned short u16;
typedef unsigned int u32;
typedef unsigned long long u64;

#define T_LEN 256
#define STEP_U16 32768          // one step's fragment set: 16kt*4nt*512 u16 = 64KB
#define CHUNK_U16 512

// workspace layout (bytes)
#define OFF_X0 0u
#define SZ_X0 (256u * 65536u)   // x0 fragments [t][kt][nt][lane][8] bf16, 16MB
#define OFF_Y0 (OFF_X0 + SZ_X0)
#define SZ_Y0 SZ_X0             // y (o-gate) fragments, 16MB
#define OFF_HD (OFF_Y0 + SZ_Y0)
#define SZ_HD (4u * 65536u)     // h ring: [layer][slot] 64KB each
#define OFF_POOL (OFF_HD + SZ_HD)
#define SZ_POOL (512u * 64u * 4u)
#define OFF_FLG (OFF_POOL + SZ_POOL)
#define SZ_FLG (4u * 128u * 4u) // [group(layer,sb)][128 producer waves] u32

__device__ __forceinline__ u16 f2bf(float x) {
  unsigned u = __builtin_bit_cast(unsigned, x);
  return (u16)((u + 0x7fffu + ((u >> 16) & 1u)) >> 16);
}
__device__ __forceinline__ float sigf(float x) { return 1.f / (1.f + __expf(-x)); }
__device__ __forceinline__ float tanhfast(float x) {
  float e = __expf(2.f * x);
  return 1.f - 2.f / (e + 1.f);
}

// LLC-coherent 16B load as 2x relaxed agent-scope 64-bit atomic loads (sc1).
__device__ __forceinline__ short8 ld16_llc(const u16* p) {
  const u64* q = (const u64*)p;
  u64 lo = __hip_atomic_load(q + 0, __ATOMIC_RELAXED, __HIP_MEMORY_SCOPE_AGENT);
  u64 hi = __hip_atomic_load(q + 1, __ATOMIC_RELAXED, __HIP_MEMORY_SCOPE_AGENT);
  union { u64 v[2]; short8 s; } u;
  u.v[0] = lo; u.v[1] = hi;
  return u.s;
}
__device__ __forceinline__ void st2_llc(u16* p, u16 v) {
  __hip_atomic_store(p, v, __ATOMIC_RELAXED, __HIP_MEMORY_SCOPE_AGENT);
}

__device__ __forceinline__ short8 cvt8(const float* src) {
  float4 lo = *(const float4*)src;
  float4 hi = *(const float4*)(src + 4);
  short8 fr;
  fr[0] = (short)f2bf(lo.x); fr[1] = (short)f2bf(lo.y);
  fr[2] = (short)f2bf(lo.z); fr[3] = (short)f2bf(lo.w);
  fr[4] = (short)f2bf(hi.x); fr[5] = (short)f2bf(hi.y);
  fr[6] = (short)f2bf(hi.z); fr[7] = (short)f2bf(hi.w);
  return fr;
}

// ---- embedding gather into MFMA-B fragment layout (bf16) ----
__global__ void gather_x0(const int* __restrict__ in_t, const float* __restrict__ emb,
                          u16* __restrict__ x0) {
  int gid = blockIdx.x * 256 + threadIdx.x;
  int c = gid >> 6, lane = gid & 63;
  int t = c >> 6, rem = c & 63;
  int kt = rem >> 2, nt = rem & 3;
  int b = nt * 16 + (lane & 15);
  int k0 = kt * 32 + ((lane >> 4) * 8);
  int row = in_t[b * T_LEN + t];
  *(short8*)(x0 + (size_t)c * CHUNK_U16 + lane * 8) =
      cvt8(emb + (size_t)row * 512 + k0);
}

// ---- persistent recurrent kernel: 512 independent waves ----
// bid: group g=bid&3 (layer=g>>1, sb=g&1), unit u=bid>>2 (0..127): rb=u>>2, mt=u&3.
// Wave owns h-indices {rb*16+mt*4+q | q=lane>>4} x samples [32sb,32sb+32),
// full K=1024. A-rows gate-interleaved: m = 4*(h_local) + gate, so each
// thread's 4 accumulator regs are the 4 gates of its own h-index.
__global__ __launch_bounds__(64, 2) void lstm_persist(
    const float* __restrict__ wx, const float* __restrict__ bx,
    const float* __restrict__ wh, const float* __restrict__ bh,
    const u16* __restrict__ x0, u16* __restrict__ y0,
    u16* __restrict__ hd, float* __restrict__ pool, u32* __restrict__ flg) {
  const int lane = threadIdx.x;
  const int bid = blockIdx.x;
  const int g = bid & 3;
  const int layer = g >> 1, sb = g & 1;
  const int u = bid >> 2;
  const int rb = u >> 2, mt = u & 3;
  const int q = lane >> 4, col = lane & 15;

  // ---- weight fragments: 16 x-kt (Wx) + 16 h-kt (Wh) = 128 VGPRs ----
  short8 afrag[32];
  {
    const int m = col;
    const int h_l = rb * 16 + mt * 4 + (m >> 2);
    const int gt = m & 3;
    const float* wxrow = wx + ((size_t)(layer * 4 + gt) * 512 + h_l) * 512;
    const float* whrow = wh + ((size_t)(layer * 4 + gt) * 512 + h_l) * 512;
#pragma unroll
    for (int kt = 0; kt < 16; ++kt) {
      afrag[kt] = cvt8(wxrow + kt * 32 + q * 8);
      afrag[16 + kt] = cvt8(whrow + kt * 32 + q * 8);
    }
  }
  const int h_own = rb * 16 + mt * 4 + q;
  float bias_r[4];
#pragma unroll
  for (int r = 0; r < 4; ++r)
    bias_r[r] = bx[(layer * 4 + r) * 512 + h_own] + bh[(layer * 4 + r) * 512 + h_own];

  const u16* xl = (layer == 0) ? x0 : y0;
  u16* hdl = hd + (size_t)layer * 2 * STEP_U16;
  u32* fl_own = flg + g * 128 + u;
  const u64* fg_h = (const u64*)(flg + g * 128);    // own (layer,sb) group
  const u64* fg_y = (const u64*)(flg + sb * 128);   // layer0 group, same sb

  float2 cst = {0.f, 0.f};
  float2 opool = {0.f, 0.f};
  const int kt2 = h_own >> 5, jj = h_own & 7;
  const int lp = col + 16 * ((h_own >> 3) & 3);

  for (int t = 0; t < T_LEN; ++t) {
    // ---- poll producer flags (relaxed sc1, one u64 per lane) ----
    {
      const u32 th = (u32)t, ty = (u32)(t + 1);
      for (;;) {
        u64 v = __hip_atomic_load(fg_h + lane, __ATOMIC_RELAXED,
                                  __HIP_MEMORY_SCOPE_AGENT);
        int ok = (int)(((u32)v >= th) & ((u32)(v >> 32) >= th));
        if (layer == 1) {
          u64 w2 = __hip_atomic_load(fg_y + lane, __ATOMIC_RELAXED,
                                     __HIP_MEMORY_SCOPE_AGENT);
          ok &= (int)(((u32)w2 >= ty) & ((u32)(w2 >> 32) >= ty));
        }
        if (__all(ok)) break;
        __builtin_amdgcn_s_sleep(1);
      }
      asm volatile("" ::: "memory");
    }

    const u16* xs = xl + (size_t)t * STEP_U16;
    const u16* hs = hdl + (size_t)(t & 1) * STEP_U16;
    f32x4 a0 = {}, a1 = {}, b0 = {}, b1 = {};  // split chains (even/odd kt)

    // ---- x-side K (static for L0; y via sc1 for L1) ----
#pragma unroll
    for (int kt = 0; kt < 16; ++kt) {
      const u16* p = xs + ((size_t)(kt * 4 + 2 * sb) * 64 + lane) * 8;
      short8 f0, f1;
      if (layer == 0) {
        f0 = *(const short8*)p;
        f1 = *(const short8*)(p + CHUNK_U16);
      } else {
        f0 = ld16_llc(p);
        f1 = ld16_llc(p + CHUNK_U16);
      }
      if (kt & 1) {
        b0 = __builtin_amdgcn_mfma_f32_16x16x32_bf16(afrag[kt], f0, b0, 0, 0, 0);
        b1 = __builtin_amdgcn_mfma_f32_16x16x32_bf16(afrag[kt], f1, b1, 0, 0, 0);
      } else {
        a0 = __builtin_amdgcn_mfma_f32_16x16x32_bf16(afrag[kt], f0, a0, 0, 0, 0);
        a1 = __builtin_amdgcn_mfma_f32_16x16x32_bf16(afrag[kt], f1, a1, 0, 0, 0);
      }
    }
    // ---- h-side K (sc1 exchange) ----
#pragma unroll
    for (int kt = 0; kt < 16; ++kt) {
      const u16* p = hs + ((size_t)(kt * 4 + 2 * sb) * 64 + lane) * 8;
      short8 f0 = ld16_llc(p);
      short8 f1 = ld16_llc(p + CHUNK_U16);
      if (kt & 1) {
        b0 = __builtin_amdgcn_mfma_f32_16x16x32_bf16(afrag[16 + kt], f0, b0, 0, 0, 0);
        b1 = __builtin_amdgcn_mfma_f32_16x16x32_bf16(afrag[16 + kt], f1, b1, 0, 0, 0);
      } else {
        a0 = __builtin_amdgcn_mfma_f32_16x16x32_bf16(afrag[16 + kt], f0, a0, 0, 0, 0);
        a1 = __builtin_amdgcn_mfma_f32_16x16x32_bf16(afrag[16 + kt], f1, a1, 0, 0, 0);
      }
    }

    // ---- gates fully in-register; scatter c (and y for L0) via sc1 ----
    u16* hdst = hdl + (size_t)((t + 1) & 1) * STEP_U16;
#pragma unroll
    for (int ntl = 0; ntl < 2; ++ntl) {
      f32x4 acc = ntl ? (a1 + b1) : (a0 + b0);
      const float ig = sigf(acc[0] + bias_r[0]);
      const float fg = sigf(acc[1] + bias_r[1]);
      const float gg = tanhfast(acc[2] + bias_r[2]);
      const float og = sigf(acc[3] + bias_r[3]);
      const float cp = ntl ? cst.y : cst.x;
      const float cn = fg * cp + ig * gg;   // c input = prev h_new (unpack bug)
      const float hn = og * tanhfast(cn);
      if (ntl) cst.y = hn; else cst.x = hn;
      const size_t off = ((size_t)(kt2 * 4 + 2 * sb + ntl) * 64 + lp) * 8 + jj;
      st2_llc(hdst + off, f2bf(cn));        // c_new -> next h-input (bug)
      if (layer == 0) {
        st2_llc(y0 + (size_t)t * STEP_U16 + off, f2bf(og));  // o-gate -> L1 input
      } else {
        if (ntl) opool.y += og; else opool.x += og;
      }
    }
    asm volatile("s_waitcnt vmcnt(0)" ::: "memory");
    if (lane == 0)
      __hip_atomic_store(fl_own, (u32)(t + 1), __ATOMIC_RELAXED,
                         __HIP_MEMORY_SCOPE_AGENT);
  }

  if (layer == 1) {
    pool[(size_t)h_own * 64 + sb * 32 + col] = opool.x;
    pool[(size_t)h_own * 64 + sb * 32 + 16 + col] = opool.y;
  }
}

// ---- final pooled @ wo.T + bo -> sigmoid ----
__global__ void finalize_k(const float* __restrict__ pool, const float* __restrict__ wo,
                           const float* __restrict__ bo, float* __restrict__ out) {
  const int b = threadIdx.x;
  float s = 0.f;
  for (int h = 0; h < 512; ++h) s += pool[h * 64 + b] * wo[h];
  out[b] = sigf(s * (1.f / 256.f) + bo[0]);
}

extern "C" void kernel_launch(void* const* d_in, const int* in_sizes, int n_in,
                              void* d_out, int out_size, void* d_ws, size_t ws_size,
                              hipStream_t stream) {
  const int* in_t = (const int*)d_in[0];
  const float* emb = (const float*)d_in[1];
  const float* wx = (const float*)d_in[2];
  const float* bx = (const float*)d_in[3];
  const float* wh = (const float*)d_in[4];
  const float* bh = (const float*)d_in[5];
  const float* wo = (const float*)d_in[6];
  const float* bo = (const float*)d_in[7];
  float* out = (float*)d_out;
  char* ws = (char*)d_ws;
  u16* x0 = (u16*)(ws + OFF_X0);
  u16* y0 = (u16*)(ws + OFF_Y0);
  u16* hd = (u16*)(ws + OFF_HD);
  float* pool = (float*)(ws + OFF_POOL);
  u32* flg = (u32*)(ws + OFF_FLG);

  hipMemsetAsync(ws + OFF_HD, 0, SZ_HD, stream);    // h(0) = 0
  hipMemsetAsync(ws + OFF_FLG, 0, SZ_FLG, stream);  // step flags
  gather_x0<<<4096, 256, 0, stream>>>(in_t, emb, x0);
  lstm_persist<<<512, 64, 0, stream>>>(wx, bx, wh, bh, x0, y0, hd, pool, flg);
  finalize_k<<<1, 64, 0, stream>>>(pool, wo, bo, out);
}

// Round 6
// 2876.473 us; speedup vs baseline: 1.0260x; 1.0260x over previous
//
#include <hip/hip_runtime.h>

typedef __attribute__((ext_vector_type(8))) short short8;
typedef __attribute__((ext_vector_type(4))) float f32x4;
typedef unsigned short u16;
typedef unsigned int u32;
typedef unsigned long long u64;

#define T_LEN 256
#define STEP_U16 32768          // one step's fragment set: 16kt*4nt*512 u16 = 64KB
#define CHUNK_U16 512

// workspace layout (bytes)
#define OFF_X0 0u
#define SZ_X0 (256u * 65536u)   // x0 fragments [t][kt][nt][lane][8] bf16, 16MB
#define OFF_Y0 (OFF_X0 + SZ_X0)
#define SZ_Y0 SZ_X0             // y (o-gate) fragments, 16MB
#define OFF_HD (OFF_Y0 + SZ_Y0)
#define SZ_HD (4u * 65536u)     // h ring: [layer][slot] 64KB each
#define OFF_POOL (OFF_HD + SZ_HD)
#define SZ_POOL (512u * 64u * 4u)
#define OFF_FLG (OFF_POOL + SZ_POOL)
#define SZ_FLG (4u * 64u * 4u)  // [group(layer,sb)][64 units] u32

__device__ __forceinline__ u16 f2bf(float x) {
  unsigned u = __builtin_bit_cast(unsigned, x);
  return (u16)((u + 0x7fffu + ((u >> 16) & 1u)) >> 16);
}
__device__ __forceinline__ float sigf(float x) { return 1.f / (1.f + __expf(-x)); }
__device__ __forceinline__ float tanhfast(float x) {
  float e = __expf(2.f * x);
  return 1.f - 2.f / (e + 1.f);
}

// LLC-coherent 16B load as 2x relaxed agent-scope 64-bit atomic loads (sc1).
__device__ __forceinline__ short8 ld16_llc(const u16* p) {
  const u64* q = (const u64*)p;
  u64 lo = __hip_atomic_load(q + 0, __ATOMIC_RELAXED, __HIP_MEMORY_SCOPE_AGENT);
  u64 hi = __hip_atomic_load(q + 1, __ATOMIC_RELAXED, __HIP_MEMORY_SCOPE_AGENT);
  union { u64 v[2]; short8 s; } u;
  u.v[0] = lo; u.v[1] = hi;
  return u.s;
}
__device__ __forceinline__ void st2_llc(u16* p, u16 v) {
  __hip_atomic_store(p, v, __ATOMIC_RELAXED, __HIP_MEMORY_SCOPE_AGENT);
}

__device__ __forceinline__ short8 cvt8(const float* src) {
  float4 lo = *(const float4*)src;
  float4 hi = *(const float4*)(src + 4);
  short8 fr;
  fr[0] = (short)f2bf(lo.x); fr[1] = (short)f2bf(lo.y);
  fr[2] = (short)f2bf(lo.z); fr[3] = (short)f2bf(lo.w);
  fr[4] = (short)f2bf(hi.x); fr[5] = (short)f2bf(hi.y);
  fr[6] = (short)f2bf(hi.z); fr[7] = (short)f2bf(hi.w);
  return fr;
}

// ---- embedding gather into MFMA-B fragment layout (bf16) ----
__global__ void gather_x0(const int* __restrict__ in_t, const float* __restrict__ emb,
                          u16* __restrict__ x0) {
  int gid = blockIdx.x * 256 + threadIdx.x;
  int c = gid >> 6, lane = gid & 63;
  int t = c >> 6, rem = c & 63;
  int kt = rem >> 2, nt = rem & 3;
  int b = nt * 16 + (lane & 15);
  int k0 = kt * 32 + ((lane >> 4) * 8);
  int row = in_t[b * T_LEN + t];
  *(short8*)(x0 + (size_t)c * CHUNK_U16 + lane * 8) =
      cvt8(emb + (size_t)row * 512 + k0);
}

// ---- persistent recurrent kernel: 256 independent fat waves ----
// bid: group g=bid&3 (layer=g>>1, sb=g&1), unit u=bid>>2 (0..63).
// Wave owns h-indices [u*8, u*8+8) (32 gate-rows, 2 m-tiles) x samples
// [32sb,32sb+32), full K=1024. Row map: m = 4*h_local + gate, so each
// thread's 4 acc regs per (mt2,ntl) are the 4 gates of one h-index.
__global__ __launch_bounds__(64, 1) void lstm_persist(
    const float* __restrict__ wx, const float* __restrict__ bx,
    const float* __restrict__ wh, const float* __restrict__ bh,
    const u16* __restrict__ x0, u16* __restrict__ y0,
    u16* __restrict__ hd, float* __restrict__ pool, u32* __restrict__ flg) {
  const int lane = threadIdx.x;
  const int bid = blockIdx.x;
  const int g = bid & 3;
  const int layer = g >> 1, sb = g & 1;
  const int u = bid >> 2;          // 0..63
  const int q = lane >> 4, col = lane & 15;

  // ---- weight fragments: 2 m-tiles x (16 x-kt + 16 h-kt) = 256 regs ----
  short8 afrag[2][32];
  {
    const int m = col;
    const int gt = m & 3;
#pragma unroll
    for (int mt2 = 0; mt2 < 2; ++mt2) {
      const int h_l = u * 8 + mt2 * 4 + (m >> 2);
      const float* wxrow = wx + ((size_t)(layer * 4 + gt) * 512 + h_l) * 512;
      const float* whrow = wh + ((size_t)(layer * 4 + gt) * 512 + h_l) * 512;
#pragma unroll
      for (int kt = 0; kt < 16; ++kt) {
        afrag[mt2][kt] = cvt8(wxrow + kt * 32 + q * 8);
        afrag[mt2][16 + kt] = cvt8(whrow + kt * 32 + q * 8);
      }
    }
  }
  const int ho0 = u * 8 + q;        // h_own for mt2=0
  const int ho1 = u * 8 + 4 + q;    // h_own for mt2=1
  float bias0[4], bias1[4];
#pragma unroll
  for (int r = 0; r < 4; ++r) {
    bias0[r] = bx[(layer * 4 + r) * 512 + ho0] + bh[(layer * 4 + r) * 512 + ho0];
    bias1[r] = bx[(layer * 4 + r) * 512 + ho1] + bh[(layer * 4 + r) * 512 + ho1];
  }

  const u16* xl = (layer == 0) ? x0 : y0;
  u16* hdl = hd + (size_t)layer * 2 * STEP_U16;
  u32* fl_own = flg + g * 64 + u;
  const u32* fg_h = flg + g * 64;   // own (layer,sb) group, 64 units
  const u32* fg_y = flg + sb * 64;  // layer0 group, same sb

  float c00 = 0.f, c01 = 0.f, c10 = 0.f, c11 = 0.f;   // cst[mt2][ntl]
  float o00 = 0.f, o01 = 0.f, o10 = 0.f, o11 = 0.f;   // opool[mt2][ntl]
  // producer scatter constants: kt2 = u>>2, z = u&3, j = mt2*4+q
  const int lp = col + 16 * (u & 3);
  const size_t cbase = ((size_t)((u >> 2) * 4 + 2 * sb) * 64 + lp) * 8;

  for (int t = 0; t < T_LEN; ++t) {
    f32x4 a00 = {}, a01 = {}, a10 = {}, a11 = {};  // acc[mt2][ntl]

    if (layer == 1) {
      // ---- L1: poll y(t) ready (flag t+1) and own h flags (t) together ----
      const u32 ty = (u32)(t + 1), th = (u32)t;
      for (;;) {
        u32 vy = __hip_atomic_load(fg_y + lane, __ATOMIC_RELAXED,
                                   __HIP_MEMORY_SCOPE_AGENT);
        u32 vh = __hip_atomic_load(fg_h + lane, __ATOMIC_RELAXED,
                                   __HIP_MEMORY_SCOPE_AGENT);
        if (__all((int)((vy >= ty) & (vh >= th)))) break;
        __builtin_amdgcn_s_sleep(1);
      }
      asm volatile("" ::: "memory");
      const u16* xs = xl + (size_t)t * STEP_U16;
#pragma unroll
      for (int kt = 0; kt < 16; ++kt) {
        const u16* p = xs + ((size_t)(kt * 4 + 2 * sb) * 64 + lane) * 8;
        short8 f0 = ld16_llc(p);
        short8 f1 = ld16_llc(p + CHUNK_U16);
        a00 = __builtin_amdgcn_mfma_f32_16x16x32_bf16(afrag[0][kt], f0, a00, 0, 0, 0);
        a10 = __builtin_amdgcn_mfma_f32_16x16x32_bf16(afrag[1][kt], f0, a10, 0, 0, 0);
        a01 = __builtin_amdgcn_mfma_f32_16x16x32_bf16(afrag[0][kt], f1, a01, 0, 0, 0);
        a11 = __builtin_amdgcn_mfma_f32_16x16x32_bf16(afrag[1][kt], f1, a11, 0, 0, 0);
      }
    } else {
      // ---- L0: x-phase first (static input, no dependency) ----
      const u16* xs = xl + (size_t)t * STEP_U16;
#pragma unroll
      for (int kt = 0; kt < 16; ++kt) {
        const u16* p = xs + ((size_t)(kt * 4 + 2 * sb) * 64 + lane) * 8;
        short8 f0 = *(const short8*)p;
        short8 f1 = *(const short8*)(p + CHUNK_U16);
        a00 = __builtin_amdgcn_mfma_f32_16x16x32_bf16(afrag[0][kt], f0, a00, 0, 0, 0);
        a10 = __builtin_amdgcn_mfma_f32_16x16x32_bf16(afrag[1][kt], f0, a10, 0, 0, 0);
        a01 = __builtin_amdgcn_mfma_f32_16x16x32_bf16(afrag[0][kt], f1, a01, 0, 0, 0);
        a11 = __builtin_amdgcn_mfma_f32_16x16x32_bf16(afrag[1][kt], f1, a11, 0, 0, 0);
      }
      // ---- then poll own h flags ----
      const u32 th = (u32)t;
      for (;;) {
        u32 vh = __hip_atomic_load(fg_h + lane, __ATOMIC_RELAXED,
                                   __HIP_MEMORY_SCOPE_AGENT);
        if (__all((int)(vh >= th))) break;
        __builtin_amdgcn_s_sleep(1);
      }
      asm volatile("" ::: "memory");
    }

    // ---- h-phase (critical): sc1 loads + MFMA ----
    {
      const u16* hs = hdl + (size_t)(t & 1) * STEP_U16;
#pragma unroll
      for (int kt = 0; kt < 16; ++kt) {
        const u16* p = hs + ((size_t)(kt * 4 + 2 * sb) * 64 + lane) * 8;
        short8 f0 = ld16_llc(p);
        short8 f1 = ld16_llc(p + CHUNK_U16);
        a00 = __builtin_amdgcn_mfma_f32_16x16x32_bf16(afrag[0][16 + kt], f0, a00, 0, 0, 0);
        a10 = __builtin_amdgcn_mfma_f32_16x16x32_bf16(afrag[1][16 + kt], f0, a10, 0, 0, 0);
        a01 = __builtin_amdgcn_mfma_f32_16x16x32_bf16(afrag[0][16 + kt], f1, a01, 0, 0, 0);
        a11 = __builtin_amdgcn_mfma_f32_16x16x32_bf16(afrag[1][16 + kt], f1, a11, 0, 0, 0);
      }
    }

    // ---- gates fully in-register; scatter c (and y for L0) via sc1 ----
    u16* hdst = hdl + (size_t)((t + 1) & 1) * STEP_U16;
    u16* ydst = y0 + (size_t)t * STEP_U16;
#define GATE(ACC, BIAS, CST, OPL, MT2, NTL)                                   \
    {                                                                          \
      const float ig = sigf(ACC[0] + BIAS[0]);                                 \
      const float fg = sigf(ACC[1] + BIAS[1]);                                 \
      const float gg = tanhfast(ACC[2] + BIAS[2]);                             \
      const float og = sigf(ACC[3] + BIAS[3]);                                 \
      const float cn = fg * CST + ig * gg;  /* c in = prev h_new (bug) */      \
      const float hn = og * tanhfast(cn);                                      \
      CST = hn;                                                                \
      const size_t off = cbase + (size_t)(NTL) * CHUNK_U16 + (MT2) * 4 + q;    \
      st2_llc(hdst + off, f2bf(cn));        /* c_new -> next h-input (bug) */  \
      if (layer == 0) st2_llc(ydst + off, f2bf(og));                           \
      else OPL += og;                                                          \
    }
    GATE(a00, bias0, c00, o00, 0, 0)
    GATE(a01, bias0, c01, o01, 0, 1)
    GATE(a10, bias1, c10, o10, 1, 0)
    GATE(a11, bias1, c11, o11, 1, 1)
#undef GATE
    asm volatile("s_waitcnt vmcnt(0)" ::: "memory");
    if (lane == 0)
      __hip_atomic_store(fl_own, (u32)(t + 1), __ATOMIC_RELAXED,
                         __HIP_MEMORY_SCOPE_AGENT);
  }

  if (layer == 1) {
    pool[(size_t)ho0 * 64 + sb * 32 + col] = o00;
    pool[(size_t)ho0 * 64 + sb * 32 + 16 + col] = o01;
    pool[(size_t)ho1 * 64 + sb * 32 + col] = o10;
    pool[(size_t)ho1 * 64 + sb * 32 + 16 + col] = o11;
  }
}

// ---- final pooled @ wo.T + bo -> sigmoid ----
__global__ void finalize_k(const float* __restrict__ pool, const float* __restrict__ wo,
                           const float* __restrict__ bo, float* __restrict__ out) {
  const int b = threadIdx.x;
  float s = 0.f;
  for (int h = 0; h < 512; ++h) s += pool[h * 64 + b] * wo[h];
  out[b] = sigf(s * (1.f / 256.f) + bo[0]);
}

extern "C" void kernel_launch(void* const* d_in, const int* in_sizes, int n_in,
                              void* d_out, int out_size, void* d_ws, size_t ws_size,
                              hipStream_t stream) {
  const int* in_t = (const int*)d_in[0];
  const float* emb = (const float*)d_in[1];
  const float* wx = (const float*)d_in[2];
  const float* bx = (const float*)d_in[3];
  const float* wh = (const float*)d_in[4];
  const float* bh = (const float*)d_in[5];
  const float* wo = (const float*)d_in[6];
  const float* bo = (const float*)d_in[7];
  float* out = (float*)d_out;
  char* ws = (char*)d_ws;
  u16* x0 = (u16*)(ws + OFF_X0);
  u16* y0 = (u16*)(ws + OFF_Y0);
  u16* hd = (u16*)(ws + OFF_HD);
  float* pool = (float*)(ws + OFF_POOL);
  u32* flg = (u32*)(ws + OFF_FLG);

  hipMemsetAsync(ws + OFF_HD, 0, SZ_HD, stream);    // h(0) = 0
  hipMemsetAsync(ws + OFF_FLG, 0, SZ_FLG, stream);  // step flags
  gather_x0<<<4096, 256, 0, stream>>>(in_t, emb, x0);
  lstm_persist<<<256, 64, 0, stream>>>(wx, bx, wh, bh, x0, y0, hd, pool, flg);
  finalize_k<<<1, 64, 0, stream>>>(pool, wo, bo, out);
}

// Round 7
// 1220.523 us; speedup vs baseline: 2.4181x; 2.3568x over previous
//
#include <hip/hip_runtime.h>

typedef __attribute__((ext_vector_type(8))) short short8;
typedef __attribute__((ext_vector_type(4))) float f32x4;
typedef unsigned short u16;
typedef unsigned int u32;
typedef unsigned long long u64;

#define T_LEN 256
#define STEP_U16 32768          // one step's fragment set: 16kt*4nt*512 u16 = 64KB
#define CHUNK_U16 512

// workspace layout (bytes)
#define OFF_X0 0u
#define SZ_X0 (256u * 65536u)   // x0 fragments [t][kt][nt][lane][8] bf16, 16MB
#define OFF_Y0 (OFF_X0 + SZ_X0)
#define SZ_Y0 SZ_X0             // y (o-gate) fragments, 16MB
#define OFF_HD (OFF_Y0 + SZ_Y0)
#define SZ_HD (4u * 65536u)     // h ring: [layer][slot] 64KB each
#define OFF_POOL (OFF_HD + SZ_HD)
#define SZ_POOL (512u * 64u * 4u)
#define OFF_HFLG (OFF_POOL + SZ_POOL)
#define SZ_HFLG (4u * 32u * 128u)   // [group(layer,sb)][32 units] 128B-strided
#define OFF_YFLG (OFF_HFLG + SZ_HFLG)
#define SZ_YFLG (2u * 32u * 128u)   // [sb][32 units] 128B-strided

__device__ __forceinline__ u16 f2bf(float x) {
  unsigned u = __builtin_bit_cast(unsigned, x);
  return (u16)((u + 0x7fffu + ((u >> 16) & 1u)) >> 16);
}
__device__ __forceinline__ float sigf(float x) { return 1.f / (1.f + __expf(-x)); }
__device__ __forceinline__ float tanhfast(float x) {
  float e = __expf(2.f * x);
  return 1.f - 2.f / (e + 1.f);
}

// LLC-coherent 16B ops as relaxed agent-scope 64-bit atomics (sc1, no inv/wb).
__device__ __forceinline__ short8 ld16_llc(const u16* p) {
  const u64* q = (const u64*)p;
  u64 lo = __hip_atomic_load(q + 0, __ATOMIC_RELAXED, __HIP_MEMORY_SCOPE_AGENT);
  u64 hi = __hip_atomic_load(q + 1, __ATOMIC_RELAXED, __HIP_MEMORY_SCOPE_AGENT);
  union { u64 v[2]; short8 s; } u;
  u.v[0] = lo; u.v[1] = hi;
  return u.s;
}
__device__ __forceinline__ void st16_llc(u16* p, short8 v) {
  union { short8 s; u64 q[2]; } u;
  u.s = v;
  u64* d = (u64*)p;
  __hip_atomic_store(d + 0, u.q[0], __ATOMIC_RELAXED, __HIP_MEMORY_SCOPE_AGENT);
  __hip_atomic_store(d + 1, u.q[1], __ATOMIC_RELAXED, __HIP_MEMORY_SCOPE_AGENT);
}

__device__ __forceinline__ short8 cvt8(const float* src) {
  float4 lo = *(const float4*)src;
  float4 hi = *(const float4*)(src + 4);
  short8 fr;
  fr[0] = (short)f2bf(lo.x); fr[1] = (short)f2bf(lo.y);
  fr[2] = (short)f2bf(lo.z); fr[3] = (short)f2bf(lo.w);
  fr[4] = (short)f2bf(hi.x); fr[5] = (short)f2bf(hi.y);
  fr[6] = (short)f2bf(hi.z); fr[7] = (short)f2bf(hi.w);
  return fr;
}

// poll 32 producer flags (128B-strided, lanes 0-31; lanes 32-63 mirror)
__device__ __forceinline__ void poll32(const u32* base, int lane, u32 tgt) {
  const u32* pf = base + (lane & 31) * 32;
  for (;;) {
    u32 v = __hip_atomic_load(pf, __ATOMIC_RELAXED, __HIP_MEMORY_SCOPE_AGENT);
    if (__all((int)(v >= tgt))) break;
    __builtin_amdgcn_s_sleep(1);
  }
  asm volatile("" ::: "memory");
}

// ---- embedding gather into MFMA-B fragment layout (bf16) ----
__global__ void gather_x0(const int* __restrict__ in_t, const float* __restrict__ emb,
                          u16* __restrict__ x0) {
  int gid = blockIdx.x * 256 + threadIdx.x;
  int c = gid >> 6, lane = gid & 63;
  int t = c >> 6, rem = c & 63;
  int kt = rem >> 2, nt = rem & 3;
  int b = nt * 16 + (lane & 15);
  int k0 = kt * 32 + ((lane >> 4) * 8);
  int row = in_t[b * T_LEN + t];
  *(short8*)(x0 + (size_t)c * CHUNK_U16 + lane * 8) =
      cvt8(emb + (size_t)row * 512 + k0);
}

// ---- persistent recurrent kernel ----
// 128 blocks x 256 threads. bid: g=bid&3 (layer=g>>1, sb=g&1), u=bid>>2 (0..31).
// Unit: h-indices [16u,16u+16) (64 gate-rows, m = 4*h_local+gate) x samples
// [32sb,32sb+32). Wave w: K-slice [256w,256w+256): w<2 x-side (Wx), w>=2 h-side (Wh).
__global__ __launch_bounds__(256, 1) void lstm_persist(
    const float* __restrict__ wx, const float* __restrict__ bx,
    const float* __restrict__ wh, const float* __restrict__ bh,
    const u16* __restrict__ x0, u16* __restrict__ y0,
    u16* __restrict__ hd, float* __restrict__ pool,
    u32* __restrict__ hflg, u32* __restrict__ yflg) {
  __shared__ float part[4][64][32];   // [wave][gate-row][sample]
  __shared__ u16 c_lds[32][16];       // [sample][h_local]
  __shared__ u16 o_lds[32][16];

  const int tid = threadIdx.x;
  const int w = tid >> 6, lane = tid & 63;
  const int q = lane >> 4, col = lane & 15;
  const int bid = blockIdx.x;
  const int g = bid & 3;
  const int layer = g >> 1, sb = g & 1;
  const int u = bid >> 2;          // 0..31
  const int side = w >> 1;         // 0: x (Wx), 1: h (Wh)

  // ---- weight fragments: 4 m-tiles x 8 k-steps = 128 VGPRs ----
  short8 afrag[4][8];
  {
    const int gt = col & 3;
    const int kb = (w & 1) * 256 + q * 8;   // k within this side's 512
#pragma unroll
    for (int mt = 0; mt < 4; ++mt) {
      const int h_l = u * 16 + mt * 4 + (col >> 2);
      const float* wrow = (side == 0 ? wx : wh) +
                          ((size_t)(layer * 4 + gt) * 512 + h_l) * 512;
#pragma unroll
      for (int ks = 0; ks < 8; ++ks)
        afrag[mt][ks] = cvt8(wrow + kb + ks * 32);
    }
  }
  // epilogue ownership: pairs (hl,bl) and (hl+8,bl)
  const int hl = tid >> 5, bl = tid & 31;
  float bias0[4], bias1[4];
#pragma unroll
  for (int r = 0; r < 4; ++r) {
    const int h0 = u * 16 + hl, h1 = u * 16 + 8 + hl;
    bias0[r] = bx[(layer * 4 + r) * 512 + h0] + bh[(layer * 4 + r) * 512 + h0];
    bias1[r] = bx[(layer * 4 + r) * 512 + h1] + bh[(layer * 4 + r) * 512 + h1];
  }

  const u16* xl = (layer == 0) ? x0 : y0;
  u16* hdl = hd + (size_t)layer * 2 * STEP_U16;
  u32* hf_own = hflg + ((size_t)g * 32 + u) * 32;
  const u32* hf_grp = hflg + (size_t)g * 32 * 32;
  u32* yf_own = yflg + ((size_t)sb * 32 + u) * 32;
  const u32* yf_grp = yflg + (size_t)sb * 32 * 32;

  float2 cst = {0.f, 0.f};
  float2 opool = {0.f, 0.f};

  for (int t = 0; t < T_LEN; ++t) {
    // ---- compute phase (per-wave) ----
    {
      const u16* src;
      bool plain;
      if (side == 0) {
        src = xl + (size_t)t * STEP_U16;
        plain = (layer == 0);
        if (layer == 1) poll32(yf_grp, lane, (u32)(t + 1));
      } else {
        src = hdl + (size_t)(t & 1) * STEP_U16;
        plain = false;
        poll32(hf_grp, lane, (u32)t);
      }
      f32x4 acc[4][2] = {};
#pragma unroll
      for (int ks = 0; ks < 8; ++ks) {
        const int ktl = (w & 1) * 8 + ks;   // local kt within step buffer
        const u16* p = src + ((size_t)(ktl * 4 + 2 * sb) * 64 + lane) * 8;
        short8 f0, f1;
        if (plain) {
          f0 = *(const short8*)p;
          f1 = *(const short8*)(p + CHUNK_U16);
        } else {
          f0 = ld16_llc(p);
          f1 = ld16_llc(p + CHUNK_U16);
        }
#pragma unroll
        for (int mt = 0; mt < 4; ++mt) {
          acc[mt][0] = __builtin_amdgcn_mfma_f32_16x16x32_bf16(afrag[mt][ks], f0,
                                                               acc[mt][0], 0, 0, 0);
          acc[mt][1] = __builtin_amdgcn_mfma_f32_16x16x32_bf16(afrag[mt][ks], f1,
                                                               acc[mt][1], 0, 0, 0);
        }
      }
      // partials -> LDS (C/D layout: col=lane&15, row=4*(lane>>4)+r)
#pragma unroll
      for (int mt = 0; mt < 4; ++mt)
#pragma unroll
        for (int ntl = 0; ntl < 2; ++ntl)
#pragma unroll
          for (int r = 0; r < 4; ++r)
            part[w][mt * 16 + q * 4 + r][ntl * 16 + col] = acc[mt][ntl][r];
    }
    __syncthreads();   // barrier 1: partials ready

    // ---- epilogue: 4-way reduce + gates; 2 (h,b) pairs per thread ----
#pragma unroll
    for (int P = 0; P < 2; ++P) {
      const int hloc = hl + P * 8;
      float v[4];
#pragma unroll
      for (int gt = 0; gt < 4; ++gt) {
        const int row = hloc * 4 + gt;
        v[gt] = part[0][row][bl] + part[1][row][bl] + part[2][row][bl] +
                part[3][row][bl] + (P ? bias1[gt] : bias0[gt]);
      }
      const float ig = sigf(v[0]);
      const float fg = sigf(v[1]);
      const float gg = tanhfast(v[2]);
      const float og = sigf(v[3]);
      const float cp = P ? cst.y : cst.x;
      const float cn = fg * cp + ig * gg;   // c input = prev h_new (unpack bug)
      const float hn = og * tanhfast(cn);
      if (P) cst.y = hn; else cst.x = hn;
      c_lds[bl][hloc] = f2bf(cn);           // c_new -> next h-input (bug)
      if (layer == 0) {
        o_lds[bl][hloc] = f2bf(og);         // o-gate -> L1 input sequence
      } else {
        if (P) opool.y += og; else opool.x += og;
      }
    }
    __syncthreads();   // barrier 2: c_lds/o_lds ready, part[] fully read

    // ---- store waves: coalesced 16B spans + private-line flags ----
    if (w == 2) {
      const int b = lane >> 1, hh = lane & 1;
      const int e = 2 * u + hh;   // global h span index (8 h each)
      const size_t off = ((size_t)((e >> 2) * 4 + sb * 2 + (b >> 4)) * 64 +
                          (e & 3) * 16 + (b & 15)) * 8;
      st16_llc(hdl + (size_t)((t + 1) & 1) * STEP_U16 + off,
               *(const short8*)&c_lds[b][hh * 8]);
      asm volatile("s_waitcnt vmcnt(0)" ::: "memory");
      if (lane == 0)
        __hip_atomic_store(hf_own, (u32)(t + 1), __ATOMIC_RELAXED,
                           __HIP_MEMORY_SCOPE_AGENT);
    } else if (w == 3 && layer == 0) {
      const int b = lane >> 1, hh = lane & 1;
      const int e = 2 * u + hh;
      const size_t off = ((size_t)((e >> 2) * 4 + sb * 2 + (b >> 4)) * 64 +
                          (e & 3) * 16 + (b & 15)) * 8;
      st16_llc(y0 + (size_t)t * STEP_U16 + off, *(const short8*)&o_lds[b][hh * 8]);
      asm volatile("s_waitcnt vmcnt(0)" ::: "memory");
      if (lane == 0)
        __hip_atomic_store(yf_own, (u32)(t + 1), __ATOMIC_RELAXED,
                           __HIP_MEMORY_SCOPE_AGENT);
    }
  }

  if (layer == 1) {
    pool[(size_t)(u * 16 + hl) * 64 + sb * 32 + bl] = opool.x;
    pool[(size_t)(u * 16 + 8 + hl) * 64 + sb * 32 + bl] = opool.y;
  }
}

// ---- final pooled @ wo.T + bo -> sigmoid ----
__global__ void finalize_k(const float* __restrict__ pool, const float* __restrict__ wo,
                           const float* __restrict__ bo, float* __restrict__ out) {
  const int b = threadIdx.x;
  float s = 0.f;
  for (int h = 0; h < 512; ++h) s += pool[h * 64 + b] * wo[h];
  out[b] = sigf(s * (1.f / 256.f) + bo[0]);
}

extern "C" void kernel_launch(void* const* d_in, const int* in_sizes, int n_in,
                              void* d_out, int out_size, void* d_ws, size_t ws_size,
                              hipStream_t stream) {
  const int* in_t = (const int*)d_in[0];
  const float* emb = (const float*)d_in[1];
  const float* wx = (const float*)d_in[2];
  const float* bx = (const float*)d_in[3];
  const float* wh = (const float*)d_in[4];
  const float* bh = (const float*)d_in[5];
  const float* wo = (const float*)d_in[6];
  const float* bo = (const float*)d_in[7];
  float* out = (float*)d_out;
  char* ws = (char*)d_ws;
  u16* x0 = (u16*)(ws + OFF_X0);
  u16* y0 = (u16*)(ws + OFF_Y0);
  u16* hd = (u16*)(ws + OFF_HD);
  float* pool = (float*)(ws + OFF_POOL);
  u32* hflg = (u32*)(ws + OFF_HFLG);
  u32* yflg = (u32*)(ws + OFF_YFLG);

  hipMemsetAsync(ws + OFF_HD, 0, SZ_HD, stream);                 // h(0) = 0
  hipMemsetAsync(ws + OFF_HFLG, 0, SZ_HFLG + SZ_YFLG, stream);   // step flags
  gather_x0<<<4096, 256, 0, stream>>>(in_t, emb, x0);
  lstm_persist<<<128, 256, 0, stream>>>(wx, bx, wh, bh, x0, y0, hd, pool,
                                        hflg, yflg);
  finalize_k<<<1, 64, 0, stream>>>(pool, wo, bo, out);
}